// Round 9
// baseline (171.917 us; speedup 1.0000x reference)
//
#include <hip/hip_runtime.h>
#include <math.h>

#define E_TYPES 20
#define NBLK 2
#define NANG 7
#define CS 384
#define CH 128
#define N_TOK (8 * 2048)
#define TOK 32
#define TPB 256                              // 4 waves
#define PREPB 256
#define GRID_M 536                           // 8 * 67 swizzle domain
#define PADN 2048

// ---- workspace: int control region ----
#define CNT_OFF 0
#define PERM_OFF 64
// ---- workspace: fragment-packed split-bf16 weights (byte offsets) ----
#define WT1_OFF (256 * 1024)
#define WT1_SZ  (20 * 8 * 24 * 2048)
#define WTR_OFF (WT1_OFF + WT1_SZ)

typedef __attribute__((ext_vector_type(8))) short bfrag;
typedef __attribute__((ext_vector_type(4))) float f32x4;
typedef unsigned int u32;
typedef __attribute__((address_space(1))) const u32 gu32;
typedef __attribute__((address_space(3))) u32 lu32;

__device__ __forceinline__ void dma16(const void* g, void* l) {
    // each lane: 16B from its own global addr -> lds_base + lane*16
    __builtin_amdgcn_global_load_lds((gu32*)g, (lu32*)l, 16, 0, 0);
}

__device__ __forceinline__ void split_bf16(float x, unsigned short& h, unsigned short& l) {
    unsigned int u = __float_as_uint(x);
    unsigned int hb = (u + 0x7FFFu + ((u >> 16) & 1u)) & 0xFFFF0000u;
    h = (unsigned short)(hb >> 16);
    float r = x - __uint_as_float(hb);
    unsigned int v = __float_as_uint(r);
    l = (unsigned short)((v + 0x7FFFu + ((v >> 16) & 1u)) >> 16);
}

// XOR swizzle: fragment (K,m) -> index; reads stay conflict-free (permutation
// within a 512B block), staging stores spread across 8 bank-groups.
__device__ __forceinline__ int SWZ(int K, int m) {
    return K * 32 + (m ^ ((4 * K) & 31));
}

// ============ prep: fused scatter + weight transpose (validated r5-r8) ============
__global__ __launch_bounds__(PREPB)
void prep_k(const float* __restrict__ Win, const float* __restrict__ Winit,
            const float* __restrict__ Wb1, const float* __restrict__ Wb2,
            const int* __restrict__ aatype, int* __restrict__ wsI,
            unsigned short* __restrict__ wt)
{
    __shared__ unsigned short tp[4][2][32][134];
    __shared__ int lh[E_TYPES], lcur[E_TYPES];
    int bid = blockIdx.x, t = threadIdx.x;

    if (bid < 64) {
        if (t < E_TYPES) { lh[t] = 0; lcur[t] = 0; }
        __syncthreads();
        for (int i = t; i < bid * 256; i += 256) atomicAdd(&lh[aatype[i]], 1);
        __syncthreads();
        int idx = bid * 256 + t;
        int e = aatype[idx];
        int r = lh[e] + atomicAdd(&lcur[e], 1);
        if (r < PADN) wsI[PERM_OFF + e * PADN + r] = idx;
        if (bid == 63) {
            __syncthreads();
            if (t < E_TYPES) wsI[CNT_OFF + t] = lh[t] + lcur[t];
        }
        return;
    }

    int w = t >> 6, lane = t & 63, lane15 = lane & 15, quad = lane >> 4;
    int wid = (bid - 64) * 4 + w;
    const float* srcbase;
    int phase1, e, kt, m4 = 0;
    if (wid < 480) {
        phase1 = 1;
        e = wid / 24; kt = wid % 24;
        srcbase = (kt < 12) ? Win   + ((size_t)e * CS + kt * 32) * CH
                            : Winit + ((size_t)e * CS + (kt - 12) * 32) * CH;
    } else {
        phase1 = 0;
        int rid = wid - 480;
        e = rid >> 4; m4 = (rid >> 2) & 3; kt = rid & 3;
        const float* W = (m4 & 1) ? Wb2 : Wb1;
        srcbase = W + (((size_t)e * NBLK + (m4 >> 1)) * CH + kt * 32) * CH;
    }

    #pragma unroll 4
    for (int i = 0; i < 16; i++) {
        int idx = i * 64 + lane;
        int row = idx >> 5, c4 = idx & 31;
        float4 v = *(const float4*)(srcbase + (size_t)row * CH + c4 * 4);
        ushort4 hv, lv;
        split_bf16(v.x, hv.x, lv.x);
        split_bf16(v.y, hv.y, lv.y);
        split_bf16(v.z, hv.z, lv.z);
        split_bf16(v.w, hv.w, lv.w);
        *(ushort4*)&tp[w][0][row][c4 * 4] = hv;
        *(ushort4*)&tp[w][1][row][c4 * 4] = lv;
    }
    #pragma unroll
    for (int nt = 0; nt < 8; nt++) {
        bfrag hb, lb;
        #pragma unroll
        for (int j = 0; j < 8; j++) {
            hb[j] = (short)tp[w][0][quad * 8 + j][nt * 16 + lane15];
            lb[j] = (short)tp[w][1][quad * 8 + j][nt * 16 + lane15];
        }
        size_t blk = phase1 ? (size_t)((e * 8 + nt) * 24 + kt)
                            : (size_t)((((e * 4 + m4) * 8) + nt) * 4 + kt);
        unsigned short* dst = wt + (phase1 ? WT1_OFF / 2 : WTR_OFF / 2)
                              + blk * 1024 + lane * 8;
        *(bfrag*)dst = hb;
        *(bfrag*)(dst + 512) = lb;
    }
}

#define MFMA(a, b, c) __builtin_amdgcn_mfma_f32_16x16x32_bf16((a), (b), (c), 0, 0, 0)

// 12 MFMAs of one k-step (2 m-tiles x 2 n-tiles, 3-term split — validated r5/r6)
#define KSTEP(AH0, AL0, AH1, AL1, BH0, BL0, BH1, BL1, ACC)   \
    ACC[0][0] = MFMA(AH0, BH0, ACC[0][0]);                   \
    ACC[0][0] = MFMA(AH0, BL0, ACC[0][0]);                   \
    ACC[0][0] = MFMA(AL0, BH0, ACC[0][0]);                   \
    ACC[0][1] = MFMA(AH0, BH1, ACC[0][1]);                   \
    ACC[0][1] = MFMA(AH0, BL1, ACC[0][1]);                   \
    ACC[0][1] = MFMA(AL0, BH1, ACC[0][1]);                   \
    ACC[1][0] = MFMA(AH1, BH0, ACC[1][0]);                   \
    ACC[1][0] = MFMA(AH1, BL0, ACC[1][0]);                   \
    ACC[1][0] = MFMA(AL1, BH0, ACC[1][0]);                   \
    ACC[1][1] = MFMA(AH1, BH1, ACC[1][1]);                   \
    ACC[1][1] = MFMA(AH1, BL1, ACC[1][1]);                   \
    ACC[1][1] = MFMA(AL1, BH1, ACC[1][1]);

// A-fragment LDS index (ushorts): [ (buf*2+plane)*256 + fi ] * 8 + j
#define AIDX(buf, p, fi) ((((buf) * 2 + (p)) * 256 + (fi)) * 8)

__global__ __launch_bounds__(TPB)
void angle_main(const float* __restrict__ s, const float* __restrict__ si,
                const float* __restrict__ b_in, const float* __restrict__ b_init2,
                const float* __restrict__ bb1, const float* __restrict__ bb2,
                const float* __restrict__ Wout, const float* __restrict__ b_out,
                const int* __restrict__ wsI, const unsigned short* __restrict__ wt,
                float* __restrict__ out)
{
    // [0,16384): A frags, 2 bufs x 2 planes x 256 frags x 16B
    // [16384,49152): B DMA slots, 4 waves x 8 slots x 1KB  (epilogue aliases here)
    __shared__ __align__(16) unsigned char smem_raw[49152];
    unsigned short* A = (unsigned short*)smem_raw;
    unsigned char*  Bb = smem_raw + 16384;
    float (*Hf)[132] = reinterpret_cast<float(*)[132]>(smem_raw + 16384);  // 16896 B
    float (*Of)[16]  = reinterpret_cast<float(*)[16]>(smem_raw + 16384 + 16896);
    __shared__ int ptok[TOK];
    __shared__ int poffs[E_TYPES + 1];

    int t = threadIdx.x;
    if (t <= E_TYPES) {
        int off = 0;
        for (int e = 0; e < t; e++)
            off += (wsI[CNT_OFF + e] + TOK - 1) & ~(TOK - 1);
        poffs[t] = off;
    }
    __syncthreads();

    int bid = blockIdx.x;
    int tile = (bid & 7) * (GRID_M / 8) + (bid >> 3);   // XCD swizzle (r7: FETCH /2)
    int pos = tile * TOK;
    if (pos >= poffs[E_TYPES]) return;
    int e = 0;
    while (e < E_TYPES - 1 && pos >= poffs[e + 1]) e++;
    int n = wsI[CNT_OFF + e] - (pos - poffs[e]);
    if (n > TOK) n = TOK;
    if (t < TOK)
        ptok[t] = wsI[PERM_OFF + e * PADN + (pos - poffs[e]) + ((t < n) ? t : 0)];

    int w = t >> 6, lane = t & 63, lane15 = lane & 15, quad = lane >> 4;
    int nc0 = (2 * w) * 16 + lane15, nc1 = nc0 + 16;
    unsigned char* Bw = Bb + w * 8192;        // this wave's 8 B-slots

    __syncthreads();

    f32x4 acc[2][2];
    {
        float bv0 = b_in[e * CH + nc0] + b_init2[e * CH + nc0];
        float bv1 = b_in[e * CH + nc1] + b_init2[e * CH + nc1];
        #pragma unroll
        for (int mt = 0; mt < 2; mt++) {
            acc[mt][0] = (f32x4){bv0, bv0, bv0, bv0};
            acc[mt][1] = (f32x4){bv1, bv1, bv1, bv1};
        }
    }

    // phase-1 A staging: thread t handles token stok, k-cols [sc*8, sc*8+8)
    int stok = t >> 3, sc = t & 7;
    const float* rowp_s  = s  + (size_t)ptok[stok] * CS;
    const float* rowp_si = si + (size_t)ptok[stok] * CS;
    int fiA = SWZ(sc, stok);

    float4 pf[2][2];
    pf[0][0] = *(const float4*)(rowp_s + sc * 8);
    pf[0][1] = *(const float4*)(rowp_s + sc * 8 + 4);

    const char* wt1b = (const char*)wt + WT1_OFF;
    const char* wtrb = (const char*)wt + WTR_OFF;

    // ---- phase 1: 12 chunks of BK=64, one barrier per chunk ----
    for (int c = 0; c < 12; c++) {
        int buf = c & 1;
        // stage A chunk from prefetch regs (split-bf16)
        #pragma unroll
        for (int q = 0; q < 2; q++) {
            float4 v = pf[buf][q];
            ushort4 hv, lv;
            split_bf16(fmaxf(v.x, 0.f), hv.x, lv.x);
            split_bf16(fmaxf(v.y, 0.f), hv.y, lv.y);
            split_bf16(fmaxf(v.z, 0.f), hv.z, lv.z);
            split_bf16(fmaxf(v.w, 0.f), hv.w, lv.w);
            *(ushort4*)&A[AIDX(buf, 0, fiA) + 4 * q] = hv;
            *(ushort4*)&A[AIDX(buf, 1, fiA) + 4 * q] = lv;
        }
        // issue this chunk's 8 B-DMAs as a batch (drained by the barrier)
        #pragma unroll
        for (int ksl = 0; ksl < 2; ksl++)
            #pragma unroll
            for (int nl = 0; nl < 2; nl++) {
                size_t blk = (size_t)((e * 8 + 2 * w + nl) * 24 + (c * 2 + ksl));
                const char* g = wt1b + blk * 2048 + lane * 16;
                dma16(g,        Bw + (ksl * 4 + nl * 2 + 0) * 1024);
                dma16(g + 1024, Bw + (ksl * 4 + nl * 2 + 1) * 1024);
            }
        __syncthreads();   // A stores (lgkm) + B DMAs (vmcnt) all ready
        // prefetch next chunk's A (lands during MFMAs)
        if (c + 1 < 12) {
            const float* rp = ((c + 1) < 6 ? rowp_s : rowp_si) + ((c + 1) % 6) * 64 + sc * 8;
            pf[buf ^ 1][0] = *(const float4*)(rp);
            pf[buf ^ 1][1] = *(const float4*)(rp + 4);
        }
        #pragma unroll
        for (int ksl = 0; ksl < 2; ksl++) {
            int K = ksl * 4 + quad;
            bfrag ah0 = *(const bfrag*)&A[AIDX(buf, 0, SWZ(K, lane15))];
            bfrag ah1 = *(const bfrag*)&A[AIDX(buf, 0, SWZ(K, 16 + lane15))];
            bfrag al0 = *(const bfrag*)&A[AIDX(buf, 1, SWZ(K, lane15))];
            bfrag al1 = *(const bfrag*)&A[AIDX(buf, 1, SWZ(K, 16 + lane15))];
            const unsigned char* bs = Bw + ksl * 4096 + lane * 16;
            bfrag bh0 = *(const bfrag*)(bs);
            bfrag bl0 = *(const bfrag*)(bs + 1024);
            bfrag bh1 = *(const bfrag*)(bs + 2048);
            bfrag bl1 = *(const bfrag*)(bs + 3072);
            KSTEP(ah0, al0, ah1, al1, bh0, bl0, bh1, bl1, acc)
        }
    }

    // ---- 2 residual blocks, 4 stages (g = 2b+stage), K=128 in 2 sub-chunks ----
    f32x4 a2[2][2];
    #pragma unroll
    for (int b = 0; b < NBLK; b++) {
        #pragma unroll
        for (int stage = 0; stage < 2; stage++) {
            int g = 2 * b + stage;
            __syncthreads();   // prior readers of A bufs done block-wide
            // write relu(h or a1) as A-frags spanning both bufs (K=128)
            #pragma unroll
            for (int mt = 0; mt < 2; mt++)
                #pragma unroll
                for (int nl = 0; nl < 2; nl++) {
                    f32x4 v = (stage == 0) ? acc[mt][nl] : a2[mt][nl];
                    int nn = 32 * w + 16 * nl + lane15;
                    int ab = w >> 1;            // nn>=64 ?
                    int K = (nn >> 3) & 7;
                    int j = nn & 7;
                    #pragma unroll
                    for (int r = 0; r < 4; r++) {
                        int m = mt * 16 + quad * 4 + r;
                        int fi = SWZ(K, m);
                        unsigned short hh, ll;
                        split_bf16(fmaxf(v[r], 0.f), hh, ll);
                        A[AIDX(ab, 0, fi) + j] = hh;
                        A[AIDX(ab, 1, fi) + j] = ll;
                    }
                }
            // issue sub0 B-DMAs
            #pragma unroll
            for (int ksl = 0; ksl < 2; ksl++)
                #pragma unroll
                for (int nl = 0; nl < 2; nl++) {
                    size_t blk = (size_t)(((e * 4 + g) * 8 + 2 * w + nl) * 4 + ksl);
                    const char* gp = wtrb + blk * 2048 + lane * 16;
                    dma16(gp,        Bw + (ksl * 4 + nl * 2 + 0) * 1024);
                    dma16(gp + 1024, Bw + (ksl * 4 + nl * 2 + 1) * 1024);
                }
            __syncthreads();   // h frags + sub0 B ready

            const float* bias = (stage == 0) ? bb1 : bb2;
            f32x4 an[2][2];
            {
                float bv0 = bias[(e * NBLK + b) * CH + nc0];
                float bv1 = bias[(e * NBLK + b) * CH + nc1];
                #pragma unroll
                for (int mt = 0; mt < 2; mt++) {
                    an[mt][0] = (f32x4){bv0, bv0, bv0, bv0};
                    an[mt][1] = (f32x4){bv1, bv1, bv1, bv1};
                }
            }
            // sub0: A buf 0 (k 0..63)
            #pragma unroll
            for (int ksl = 0; ksl < 2; ksl++) {
                int K = ksl * 4 + quad;
                bfrag ah0 = *(const bfrag*)&A[AIDX(0, 0, SWZ(K, lane15))];
                bfrag ah1 = *(const bfrag*)&A[AIDX(0, 0, SWZ(K, 16 + lane15))];
                bfrag al0 = *(const bfrag*)&A[AIDX(0, 1, SWZ(K, lane15))];
                bfrag al1 = *(const bfrag*)&A[AIDX(0, 1, SWZ(K, 16 + lane15))];
                const unsigned char* bs = Bw + ksl * 4096 + lane * 16;
                bfrag bh0 = *(const bfrag*)(bs);
                bfrag bl0 = *(const bfrag*)(bs + 1024);
                bfrag bh1 = *(const bfrag*)(bs + 2048);
                bfrag bl1 = *(const bfrag*)(bs + 3072);
                KSTEP(ah0, al0, ah1, al1, bh0, bl0, bh1, bl1, an)
            }
            // issue sub1 B-DMAs (own-wave slots; reads above already consumed)
            #pragma unroll
            for (int ksl = 0; ksl < 2; ksl++)
                #pragma unroll
                for (int nl = 0; nl < 2; nl++) {
                    size_t blk = (size_t)(((e * 4 + g) * 8 + 2 * w + nl) * 4 + 2 + ksl);
                    const char* gp = wtrb + blk * 2048 + lane * 16;
                    dma16(gp,        Bw + (ksl * 4 + nl * 2 + 0) * 1024);
                    dma16(gp + 1024, Bw + (ksl * 4 + nl * 2 + 1) * 1024);
                }
            __syncthreads();   // sub1 B ready
            // sub1: A buf 1 (k 64..127)
            #pragma unroll
            for (int ksl = 0; ksl < 2; ksl++) {
                int K = ksl * 4 + quad;
                bfrag ah0 = *(const bfrag*)&A[AIDX(1, 0, SWZ(K, lane15))];
                bfrag ah1 = *(const bfrag*)&A[AIDX(1, 0, SWZ(K, 16 + lane15))];
                bfrag al0 = *(const bfrag*)&A[AIDX(1, 1, SWZ(K, lane15))];
                bfrag al1 = *(const bfrag*)&A[AIDX(1, 1, SWZ(K, 16 + lane15))];
                const unsigned char* bs = Bw + ksl * 4096 + lane * 16;
                bfrag bh0 = *(const bfrag*)(bs);
                bfrag bl0 = *(const bfrag*)(bs + 1024);
                bfrag bh1 = *(const bfrag*)(bs + 2048);
                bfrag bl1 = *(const bfrag*)(bs + 3072);
                KSTEP(ah0, al0, ah1, al1, bh0, bl0, bh1, bl1, an)
            }
            if (stage == 0) {
                #pragma unroll
                for (int mt = 0; mt < 2; mt++)
                    #pragma unroll
                    for (int nl = 0; nl < 2; nl++) a2[mt][nl] = an[mt][nl];
            } else {
                #pragma unroll
                for (int mt = 0; mt < 2; mt++)
                    #pragma unroll
                    for (int nl = 0; nl < 2; nl++) acc[mt][nl] += an[mt][nl];
            }
        }
    }

    // ---- epilogue: relu(h) fp32 -> LDS (aliases B region, now dead) ----
    __syncthreads();
    #pragma unroll
    for (int mt = 0; mt < 2; mt++)
        #pragma unroll
        for (int nl = 0; nl < 2; nl++) {
            f32x4 v = acc[mt][nl];
            int nn = 32 * w + 16 * nl + lane15;
            #pragma unroll
            for (int r = 0; r < 4; r++)
                Hf[mt * 16 + quad * 4 + r][nn] = fmaxf(v[r], 0.f);
        }
    __syncthreads();

    const float* WoutE = Wout + (size_t)e * CH * (NANG * 2);
    const float* boutE = b_out + (size_t)e * (NANG * 2);
    for (int idx = t; idx < n * (NANG * 2); idx += TPB) {
        int i = idx / (NANG * 2);
        int o = idx % (NANG * 2);
        float v = boutE[o];
        #pragma unroll 4
        for (int k = 0; k < CH; k++)
            v = fmaf(Hf[i][k], WoutE[(size_t)k * (NANG * 2) + o], v);
        Of[i][o] = v;
    }
    __syncthreads();

    for (int idx = t; idx < n * NANG; idx += TPB) {
        int i = idx / NANG;
        int a = idx % NANG;
        float x = Of[i][2 * a];
        float y = Of[i][2 * a + 1];
        float nr = fmaxf(sqrtf(x * x + y * y), 1e-12f);
        size_t base = (size_t)ptok[i] * (NANG * 2) + 2 * a;
        out[base]     = x / nr;
        out[base + 1] = y / nr;
    }
}

extern "C" void kernel_launch(void* const* d_in, const int* in_sizes, int n_in,
                              void* d_out, int out_size, void* d_ws, size_t ws_size,
                              hipStream_t stream) {
    const float* s       = (const float*)d_in[0];
    const float* s_init  = (const float*)d_in[1];
    const int*   aatype  = (const int*)d_in[2];
    const float* Win     = (const float*)d_in[3];
    const float* b_in    = (const float*)d_in[4];
    const float* Winit   = (const float*)d_in[5];
    const float* b_init2 = (const float*)d_in[6];
    const float* Wb1     = (const float*)d_in[7];
    const float* bb1     = (const float*)d_in[8];
    const float* Wb2     = (const float*)d_in[9];
    const float* bb2     = (const float*)d_in[10];
    const float* Wout    = (const float*)d_in[11];
    const float* b_out   = (const float*)d_in[12];
    int* wsI = (int*)d_ws;
    unsigned short* wt = (unsigned short*)d_ws;
    float* out = (float*)d_out;

    hipLaunchKernelGGL(prep_k, dim3(64 + 200), dim3(PREPB), 0, stream,
                       Win, Winit, Wb1, Wb2, aatype, wsI, wt);
    hipLaunchKernelGGL(angle_main, dim3(GRID_M), dim3(TPB), 0, stream,
                       s, s_init, b_in, b_init2, bb1, bb2, Wout, b_out,
                       wsI, wt, out);
}